// Round 11
// baseline (296.702 us; speedup 1.0000x reference)
//
#include <hip/hip_runtime.h>
#include <stdint.h>

#define NN 50000
#define NE 800000
// DIM=128, HEADS=8, DK=16, rel_pri/sqrt(dk) folded into K-projection

typedef __bf16 v8bf __attribute__((ext_vector_type(8)));
typedef float  v4f  __attribute__((ext_vector_type(4)));
typedef unsigned short v8us __attribute__((ext_vector_type(8)));

#define EXP2F(x) __builtin_amdgcn_exp2f(x)   // v_exp_f32: 2^x

__device__ __forceinline__ float bf2f(unsigned short u) {
    return __uint_as_float(((unsigned)u) << 16);
}
__device__ __forceinline__ unsigned short f2bf(float f) {
    unsigned u = __float_as_uint(f);
    u += 0x7FFFu + ((u >> 16) & 1u);   // round-to-nearest-even
    return (unsigned short)(u >> 16);
}
__device__ __forceinline__ float ldf(const void* p, size_t i, int isb) {
    return isb ? bf2f(((const unsigned short*)p)[i]) : ((const float*)p)[i];
}

// ---------------------------------------------------------------------------
// Fused prep + histogram. Blocks 0..511: combined bf16 weights (transposed
// [m][col][k]) + FLAG. Blocks 512..6761: dst histogram into line-padded
// CNTP[d*16].
// ---------------------------------------------------------------------------
__global__ __launch_bounds__(128) void k_prep(
    const void* __restrict__ Wq, const void* __restrict__ bq,
    const void* __restrict__ Wk, const void* __restrict__ bk,
    const void* __restrict__ Wv, const void* __restrict__ bv,
    const void* __restrict__ Wa, const void* __restrict__ ba,
    const void* __restrict__ rel_att, const void* __restrict__ rel_msg,
    const void* __restrict__ rel_pri, const int* __restrict__ dst,
    unsigned* __restrict__ CNTP,
    int* __restrict__ FLAG, unsigned short* __restrict__ WTb,
    float* __restrict__ BC)
{
    int b = blockIdx.x;
    int j = threadIdx.x;
    if (b >= 512) {                       // histogram part
        int e = (b - 512) * 128 + j;      // 6250*128 == NE exactly
        atomicAdd(&CNTP[(unsigned)dst[e] << 4], 1u);
        return;
    }
    const unsigned rp0 = ((const unsigned*)rel_pri)[0];
    const int isb = ((rp0 & 0xFFFFu) != 0u) ? 1 : 0;
    int m = b >> 7;
    int i = b & 127;          // k index
    if (b == 0 && j == 0) FLAG[0] = isb;
    if (m == 0) {
        WTb[((size_t)(0 * 128 + j)) * 128 + i] = f2bf(ldf(Wq, i * 128 + j, isb));
        if (i == 0) BC[j] = ldf(bq, j, isb);
    } else if (m == 3) {
        WTb[((size_t)(3 * 128 + j)) * 128 + i] = f2bf(ldf(Wa, i * 128 + j, isb));
        if (i == 0) BC[3 * 128 + j] = ldf(ba, j, isb);
    } else {
        const void* W    = (m == 1) ? Wk : Wv;
        const void* bias = (m == 1) ? bk : bv;
        const void* R    = (m == 1) ? rel_att : rel_msg;
        int hh = j >> 4, jj = j & 15;
        float scale = (m == 1) ? ldf(rel_pri, hh, isb) * 0.25f : 1.0f;
        float acc = 0.f, bacc = 0.f;
        #pragma unroll
        for (int l = 0; l < 16; ++l) {
            float r = ldf(R, hh * 256 + l * 16 + jj, isb);
            acc  += ldf(W, i * 128 + hh * 16 + l, isb) * r;
            bacc += ldf(bias, hh * 16 + l, isb) * r;
        }
        WTb[((size_t)(m * 128 + j)) * 128 + i] = f2bf(acc * scale);
        if (i == 0) BC[m * 128 + j] = bacc * scale;
    }
}

// ---------------------------------------------------------------------------
// Fused MFMA QKV GEMM + CSR scan.
// Blocks 0..781: 64 rows x 128 cols GEMM, loop m=0..2 (A staged once);
//   K accumulators held through the V pass, KV stored interleaved ushort2.
// Blocks 782..879: CSR scan (512 nodes/block, 256 threads x 2), last-block
//   pattern produces BOFF; also zeroes CURP. Reuses Ah's LDS for the scan.
// ---------------------------------------------------------------------------
#define NSB 98   // ceil(NN/512)
__global__ __launch_bounds__(256) void k_qkvscan(
    const void* __restrict__ h, const unsigned short* __restrict__ WTb,
    const float* __restrict__ BC, const int* __restrict__ FLAG,
    unsigned short* __restrict__ Qb, unsigned short* __restrict__ KVb,
    const unsigned* __restrict__ CNTP, unsigned* __restrict__ CURP,
    unsigned* __restrict__ RPS, unsigned* __restrict__ BSUM,
    unsigned* __restrict__ BOFF, unsigned* __restrict__ DONE)
{
    __shared__ __align__(16) unsigned short Ah[64][136];   // +8 pad
    __shared__ __align__(16) unsigned short Bh[128][136];
    __shared__ int lastFlag;
    const int tid = threadIdx.x;

    if (blockIdx.x >= 782) {
        // ---------------- CSR scan part ----------------
        unsigned* shs = (unsigned*)&Ah[0][0];    // 257 u32 << 17 KB available
        int sb = blockIdx.x - 782;
        int g0 = sb * 512 + tid * 2, g1 = g0 + 1;
        unsigned v0 = (g0 < NN) ? CNTP[(size_t)g0 << 4] : 0u;
        unsigned v1 = (g1 < NN) ? CNTP[(size_t)g1 << 4] : 0u;
        if (g0 < NN) CURP[(size_t)g0 << 4] = 0u;
        if (g1 < NN) CURP[(size_t)g1 << 4] = 0u;
        unsigned pv = v0 + v1;
        shs[tid] = pv;
        __syncthreads();
        #pragma unroll
        for (int off = 1; off < 256; off <<= 1) {
            unsigned t = 0;
            if (tid >= off) t = shs[tid - off];
            __syncthreads();
            if (tid >= off) shs[tid] += t;
            __syncthreads();
        }
        unsigned excl = shs[tid] - pv;
        if (g0 < NN) RPS[g0] = excl;
        if (g1 < NN) RPS[g1] = excl + v0;
        if (tid == 255) atomicExch(&BSUM[sb], shs[255]);
        __syncthreads();
        if (tid == 0) {
            __threadfence();
            lastFlag = (atomicAdd(DONE, 1u) == NSB - 1);
        }
        __syncthreads();
        if (!lastFlag) return;
        unsigned bv = (tid < NSB) ? atomicAdd(&BSUM[tid], 0u) : 0u;
        __syncthreads();
        shs[tid] = bv;
        __syncthreads();
        #pragma unroll
        for (int off = 1; off < 256; off <<= 1) {
            unsigned t = 0;
            if (tid >= off) t = shs[tid - off];
            __syncthreads();
            if (tid >= off) shs[tid] += t;
            __syncthreads();
        }
        if (tid < NSB) BOFF[tid] = shs[tid] - bv;
        return;
    }

    // ---------------- QKV GEMM part ----------------
    const int isb = FLAG[0];
    const int rowBase = blockIdx.x * 64;

    if (isb) {
        #pragma unroll
        for (int i = 0; i < 4; ++i) {
            int lin = tid + i * 256;
            int row = lin >> 4, kc = (lin & 15) * 8;
            int gr = rowBase + row;
            uint4 u = make_uint4(0, 0, 0, 0);
            if (gr < NN) u = *(const uint4*)((const unsigned short*)h + (size_t)gr * 128 + kc);
            *(uint4*)&Ah[row][kc] = u;
        }
    } else {
        #pragma unroll
        for (int i = 0; i < 8; ++i) {
            int lin = tid + i * 256;
            int row = lin >> 5, c4 = (lin & 31) * 4;
            int gr = rowBase + row;
            ushort4 o = make_ushort4(0, 0, 0, 0);
            if (gr < NN) {
                float4 f = *(const float4*)((const float*)h + (size_t)gr * 128 + c4);
                o.x = f2bf(f.x); o.y = f2bf(f.y); o.z = f2bf(f.z); o.w = f2bf(f.w);
            }
            *(ushort4*)&Ah[row][c4] = o;
        }
    }

    const int w = tid >> 6, l = tid & 63;
    const int lr = l & 15, q = l >> 4;
    v4f accK[8];

    for (int m = 0; m < 3; ++m) {
        if (m) __syncthreads();
        #pragma unroll
        for (int i = 0; i < 8; ++i) {
            int lin = tid + i * 256;
            int col = lin >> 4, kc = (lin & 15) * 8;
            uint4 u = *(const uint4*)(WTb + ((size_t)(m * 128 + col)) * 128 + kc);
            *(uint4*)&Bh[col][kc] = u;
        }
        __syncthreads();

        v4f acc[8];
        #pragma unroll
        for (int nt = 0; nt < 8; ++nt) {
            float bj = BC[m * 128 + nt * 16 + lr];
            acc[nt] = (v4f){bj, bj, bj, bj};
        }
        #pragma unroll
        for (int kk = 0; kk < 4; ++kk) {
            v8bf a = *(const v8bf*)&Ah[w * 16 + lr][kk * 32 + q * 8];
            #pragma unroll
            for (int nt = 0; nt < 8; ++nt) {
                v8bf b = *(const v8bf*)&Bh[nt * 16 + lr][kk * 32 + q * 8];
                acc[nt] = __builtin_amdgcn_mfma_f32_16x16x32_bf16(a, b, acc[nt], 0, 0, 0);
            }
        }
        if (m == 0) {
            #pragma unroll
            for (int nt = 0; nt < 8; ++nt)
                #pragma unroll
                for (int r = 0; r < 4; ++r) {
                    int row = rowBase + w * 16 + q * 4 + r;
                    if (row < NN)
                        Qb[(size_t)row * 128 + nt * 16 + lr] = f2bf(acc[nt][r]);
                }
        } else if (m == 1) {
            #pragma unroll
            for (int nt = 0; nt < 8; ++nt) accK[nt] = acc[nt];
        } else {
            #pragma unroll
            for (int nt = 0; nt < 8; ++nt)
                #pragma unroll
                for (int r = 0; r < 4; ++r) {
                    int row = rowBase + w * 16 + q * 4 + r;
                    if (row < NN) {
                        ushort2 kv;
                        kv.x = f2bf(accK[nt][r]);   // K channel
                        kv.y = f2bf(acc[nt][r]);    // V channel
                        *(ushort2*)&KVb[(size_t)row * 256 + (nt * 16 + lr) * 2] = kv;
                    }
                }
        }
    }
}

// ---------------------------------------------------------------------------
// CSR fill: 4 consecutive edges per thread (int4 coalesced index loads),
// 4 independent atomics in flight, then 4 scatter stores.
// ---------------------------------------------------------------------------
__global__ __launch_bounds__(256) void k_fill(
    const int* __restrict__ src, const int* __restrict__ dst,
    const unsigned* __restrict__ RPS, const unsigned* __restrict__ BOFF,
    unsigned* __restrict__ CURP, int* __restrict__ ESRC)
{
    int t = blockIdx.x * 256 + threadIdx.x;
    if (t >= NE / 4) return;
    int e = t * 4;
    const int4 d4 = *(const int4*)(dst + e);
    const int4 s4 = *(const int4*)(src + e);
    unsigned p0 = atomicAdd(&CURP[(size_t)(unsigned)d4.x << 4], 1u);
    unsigned p1 = atomicAdd(&CURP[(size_t)(unsigned)d4.y << 4], 1u);
    unsigned p2 = atomicAdd(&CURP[(size_t)(unsigned)d4.z << 4], 1u);
    unsigned p3 = atomicAdd(&CURP[(size_t)(unsigned)d4.w << 4], 1u);
    ESRC[(int)(RPS[d4.x] + BOFF[d4.x >> 9] + p0)] = s4.x;
    ESRC[(int)(RPS[d4.y] + BOFF[d4.y >> 9] + p1)] = s4.y;
    ESRC[(int)(RPS[d4.z] + BOFF[d4.z >> 9] + p2)] = s4.z;
    ESRC[(int)(RPS[d4.w] + BOFF[d4.w >> 9] + p3)] = s4.w;
}

// ---------------------------------------------------------------------------
// Fused attention v3: one wave per dst node, 32 lanes per edge (2 edges per
// round), batch-4 rounds (8 edges), SOFTWARE-PIPELINED: round j+1's gathers
// are issued before round j's compute. No-max softmax (scores bounded).
// ---------------------------------------------------------------------------
__global__ __launch_bounds__(256) void k_attn(
    const unsigned* __restrict__ RPS, const unsigned* __restrict__ BOFF,
    const int* __restrict__ ESRC,
    const unsigned short* __restrict__ Qb, const unsigned short* __restrict__ KVb,
    unsigned short* __restrict__ Tb)
{
    int d = (blockIdx.x * 256 + threadIdx.x) >> 6;
    int lane = threadIdx.x & 63;
    int hl = lane >> 5;        // which edge of the pair
    int sub = lane & 31;       // channel group: channels sub*4 .. sub*4+3
    int beg = (int)(RPS[d] + BOFF[d >> 9]);
    int end = (d == NN - 1) ? NE : (int)(RPS[d + 1] + BOFF[(d + 1) >> 9]);
    const float LOG2E = 1.4426950408889634f;

    const ushort4 qu = *(const ushort4*)(Qb + (size_t)d * 128 + sub * 4);
    float q0 = bf2f(qu.x) * LOG2E, q1 = bf2f(qu.y) * LOG2E;
    float q2 = bf2f(qu.z) * LOG2E, q3 = bf2f(qu.w) * LOG2E;

    float s = 0.f, o0 = 0.f, o1 = 0.f, o2 = 0.f, o3 = 0.f;
    v8us kvA[4]; int vA[4];
    if (beg < end) {
        #pragma unroll
        for (int t = 0; t < 4; ++t) {
            int idx = beg + 2 * t + hl;
            vA[t] = idx < end;
            int sid = ESRC[vA[t] ? idx : end - 1];
            kvA[t] = *(const v8us*)(KVb + (size_t)sid * 256 + sub * 8);
        }
    }
    for (int j = beg; j < end; j += 8) {
        v8us kvB[4]; int vB[4] = {0, 0, 0, 0};
        int jn = j + 8;
        if (jn < end) {                   // issue next round's gathers NOW
            #pragma unroll
            for (int t = 0; t < 4; ++t) {
                int idx = jn + 2 * t + hl;
                vB[t] = idx < end;
                int sid = ESRC[vB[t] ? idx : end - 1];
                kvB[t] = *(const v8us*)(KVb + (size_t)sid * 256 + sub * 8);
            }
        }
        #pragma unroll
        for (int t = 0; t < 4; ++t) {
            float p = q0 * bf2f(kvA[t][0]) + q1 * bf2f(kvA[t][2])
                    + q2 * bf2f(kvA[t][4]) + q3 * bf2f(kvA[t][6]);
            p += __shfl_xor(p, 1);
            p += __shfl_xor(p, 2);       // per-head score in 4-lane group
            float w = vA[t] ? EXP2F(p) : 0.f;
            s  += w;
            o0 += w * bf2f(kvA[t][1]);
            o1 += w * bf2f(kvA[t][3]);
            o2 += w * bf2f(kvA[t][5]);
            o3 += w * bf2f(kvA[t][7]);
        }
        #pragma unroll
        for (int t = 0; t < 4; ++t) { kvA[t] = kvB[t]; vA[t] = vB[t]; }
    }
    // combine the two 32-lane halves
    s  += __shfl_xor(s, 32);
    o0 += __shfl_xor(o0, 32);
    o1 += __shfl_xor(o1, 32);
    o2 += __shfl_xor(o2, 32);
    o3 += __shfl_xor(o3, 32);
    float r = (s > 0.f) ? (1.0f / s) : 0.f;
    if (hl == 0) {
        ushort4 o;
        o.x = f2bf(o0 * r); o.y = f2bf(o1 * r);
        o.z = f2bf(o2 * r); o.w = f2bf(o3 * r);
        *(ushort4*)(Tb + (size_t)d * 128 + sub * 4) = o;
    }
}

// ---------------------------------------------------------------------------
// MFMA final GEMM + sigmoid-skip blend. T is bf16 (A-tile copied raw).
// ---------------------------------------------------------------------------
__global__ __launch_bounds__(256) void k_final_m(
    const unsigned short* __restrict__ Tb, const unsigned short* __restrict__ WTb,
    const float* __restrict__ BC, const void* __restrict__ h,
    const void* __restrict__ skip, const int* __restrict__ FLAG,
    void* __restrict__ out)
{
    __shared__ __align__(16) unsigned short Ah[64][136];
    __shared__ __align__(16) unsigned short Bh[128][136];
    const int isb = FLAG[0];
    const int tid = threadIdx.x;
    const int rowBase = blockIdx.x * 64;

    #pragma unroll
    for (int i = 0; i < 4; ++i) {
        int lin = tid + i * 256;
        int row = lin >> 4, kc = (lin & 15) * 8;
        int gr = rowBase + row;
        uint4 u = make_uint4(0, 0, 0, 0);
        if (gr < NN) u = *(const uint4*)(Tb + (size_t)gr * 128 + kc);
        *(uint4*)&Ah[row][kc] = u;
    }
    #pragma unroll
    for (int i = 0; i < 8; ++i) {
        int lin = tid + i * 256;
        int col = lin >> 4, kc = (lin & 15) * 8;
        uint4 u = *(const uint4*)(WTb + ((size_t)(3 * 128 + col)) * 128 + kc);
        *(uint4*)&Bh[col][kc] = u;
    }
    __syncthreads();

    const int w = tid >> 6, l = tid & 63;
    const int lr = l & 15, q = l >> 4;
    v4f acc[8];
    #pragma unroll
    for (int nt = 0; nt < 8; ++nt) {
        float bj = BC[3 * 128 + nt * 16 + lr];
        acc[nt] = (v4f){bj, bj, bj, bj};
    }
    #pragma unroll
    for (int kk = 0; kk < 4; ++kk) {
        v8bf a = *(const v8bf*)&Ah[w * 16 + lr][kk * 32 + q * 8];
        #pragma unroll
        for (int nt = 0; nt < 8; ++nt) {
            v8bf b = *(const v8bf*)&Bh[nt * 16 + lr][kk * 32 + q * 8];
            acc[nt] = __builtin_amdgcn_mfma_f32_16x16x32_bf16(a, b, acc[nt], 0, 0, 0);
        }
    }
    float skipv = ldf(skip, 0, isb);
    float alpha = 1.0f / (1.0f + __expf(-skipv));
    float beta = 1.0f - alpha;
    #pragma unroll
    for (int nt = 0; nt < 8; ++nt) {
        #pragma unroll
        for (int r = 0; r < 4; ++r) {
            int row = rowBase + w * 16 + q * 4 + r;
            if (row < NN) {
                size_t off = (size_t)row * 128 + nt * 16 + lr;
                float hv = ldf(h, off, isb);
                float o = alpha * acc[nt][r] + beta * hv;
                if (isb) ((unsigned short*)out)[off] = f2bf(o);
                else     ((float*)out)[off] = o;
            }
        }
    }
}

// ---------------------------------------------------------------------------
// ws layout (u32 offsets): FLAG 16 | BC 512 | WTb 32768(u32-equiv) |
// CNTP 800000 | DONE 16 | CURP 800000 | RPS 50048 | BSUM 128 | BOFF 128 |
// Tb NN*128us | ESRC NE | Qb NN*128us | KVb NN*256us
// ---------------------------------------------------------------------------
extern "C" void kernel_launch(void* const* d_in, const int* in_sizes, int n_in,
                              void* d_out, int out_size, void* d_ws, size_t ws_size,
                              hipStream_t stream)
{
    const void* h  = d_in[0];
    const int* src = (const int*)d_in[1];
    const int* dst = (const int*)d_in[2];
    const void* Wk = d_in[3];
    const void* bk = d_in[4];
    const void* Wq = d_in[5];
    const void* bq = d_in[6];
    const void* Wv = d_in[7];
    const void* bv = d_in[8];
    const void* Wa = d_in[9];
    const void* ba = d_in[10];
    const void* rel_att = d_in[11];
    const void* rel_msg = d_in[12];
    const void* rel_pri = d_in[13];
    const void* skip    = d_in[14];

    float* F = (float*)d_ws;
    int* FLAG      = (int*)F;
    float* BC      = F + 16;
    unsigned short* WTb = (unsigned short*)(BC + 512);
    unsigned* CNTP = (unsigned*)((float*)(BC + 512) + 32768);
    unsigned* DONE = CNTP + 800000;
    unsigned* CURP = DONE + 16;
    unsigned* RPS  = CURP + 800000;
    unsigned* BSUM = RPS + 50048;
    unsigned* BOFF = BSUM + 128;
    unsigned short* Tb = (unsigned short*)(BOFF + 128);
    int* ESRC      = (int*)(Tb + (size_t)NN * 128);
    unsigned short* Qb  = (unsigned short*)(ESRC + NE);
    unsigned short* KVb = Qb + (size_t)NN * 128;

    // zero CNTP | DONE (contiguous, 3.2 MB; CURP zeroed inside the scan)
    (void)hipMemsetAsync(CNTP, 0, (800000 + 16) * sizeof(unsigned), stream);

    k_prep<<<512 + 6250, 128, 0, stream>>>(Wq, bq, Wk, bk, Wv, bv, Wa, ba,
                                           rel_att, rel_msg, rel_pri, dst, CNTP,
                                           FLAG, WTb, BC);
    k_qkvscan<<<782 + NSB, 256, 0, stream>>>(h, WTb, BC, FLAG, Qb, KVb,
                                             CNTP, CURP, RPS, BSUM, BOFF, DONE);
    k_fill<<<(NE / 4 + 255) / 256, 256, 0, stream>>>(src, dst, RPS, BOFF, CURP, ESRC);
    k_attn<<<(NN * 64) / 256, 256, 0, stream>>>(RPS, BOFF, ESRC, Qb, KVb, Tb);
    k_final_m<<<782, 256, 0, stream>>>(Tb, WTb, BC, h, skip, FLAG, d_out);
}

// Round 12
// 259.340 us; speedup vs baseline: 1.1441x; 1.1441x over previous
//
#include <hip/hip_runtime.h>
#include <stdint.h>

#define NN 50000
#define NE 800000
// DIM=128, HEADS=8, DK=16, rel_pri/sqrt(dk) folded into K-projection

typedef __bf16 v8bf __attribute__((ext_vector_type(8)));
typedef float  v4f  __attribute__((ext_vector_type(4)));
typedef unsigned short v8us __attribute__((ext_vector_type(8)));

#define EXP2F(x) __builtin_amdgcn_exp2f(x)   // v_exp_f32: 2^x

__device__ __forceinline__ float bf2f(unsigned short u) {
    return __uint_as_float(((unsigned)u) << 16);
}
__device__ __forceinline__ unsigned short f2bf(float f) {
    unsigned u = __float_as_uint(f);
    u += 0x7FFFu + ((u >> 16) & 1u);   // round-to-nearest-even
    return (unsigned short)(u >> 16);
}
__device__ __forceinline__ float ldf(const void* p, size_t i, int isb) {
    return isb ? bf2f(((const unsigned short*)p)[i]) : ((const float*)p)[i];
}

// ---------------------------------------------------------------------------
// Fused prep + histogram-with-rank. Blocks 0..511: combined bf16 weights
// (transposed [m][col][k]) + FLAG. Blocks 512..6761: dst histogram into
// line-padded CNTP[d*16]; the atomic's return value IS the edge's rank
// within its dst bucket -> stored coalesced in RANKS (ushort).
// ---------------------------------------------------------------------------
__global__ __launch_bounds__(128) void k_prep(
    const void* __restrict__ Wq, const void* __restrict__ bq,
    const void* __restrict__ Wk, const void* __restrict__ bk,
    const void* __restrict__ Wv, const void* __restrict__ bv,
    const void* __restrict__ Wa, const void* __restrict__ ba,
    const void* __restrict__ rel_att, const void* __restrict__ rel_msg,
    const void* __restrict__ rel_pri, const int* __restrict__ dst,
    unsigned* __restrict__ CNTP, unsigned short* __restrict__ RANKS,
    int* __restrict__ FLAG, unsigned short* __restrict__ WTb,
    float* __restrict__ BC)
{
    int b = blockIdx.x;
    int j = threadIdx.x;
    if (b >= 512) {                       // histogram part
        int e = (b - 512) * 128 + j;      // 6250*128 == NE exactly
        unsigned r = atomicAdd(&CNTP[(unsigned)dst[e] << 4], 1u);
        RANKS[e] = (unsigned short)r;
        return;
    }
    const unsigned rp0 = ((const unsigned*)rel_pri)[0];
    const int isb = ((rp0 & 0xFFFFu) != 0u) ? 1 : 0;
    int m = b >> 7;
    int i = b & 127;          // k index
    if (b == 0 && j == 0) FLAG[0] = isb;
    if (m == 0) {
        WTb[((size_t)(0 * 128 + j)) * 128 + i] = f2bf(ldf(Wq, i * 128 + j, isb));
        if (i == 0) BC[j] = ldf(bq, j, isb);
    } else if (m == 3) {
        WTb[((size_t)(3 * 128 + j)) * 128 + i] = f2bf(ldf(Wa, i * 128 + j, isb));
        if (i == 0) BC[3 * 128 + j] = ldf(ba, j, isb);
    } else {
        const void* W    = (m == 1) ? Wk : Wv;
        const void* bias = (m == 1) ? bk : bv;
        const void* R    = (m == 1) ? rel_att : rel_msg;
        int hh = j >> 4, jj = j & 15;
        float scale = (m == 1) ? ldf(rel_pri, hh, isb) * 0.25f : 1.0f;
        float acc = 0.f, bacc = 0.f;
        #pragma unroll
        for (int l = 0; l < 16; ++l) {
            float r = ldf(R, hh * 256 + l * 16 + jj, isb);
            acc  += ldf(W, i * 128 + hh * 16 + l, isb) * r;
            bacc += ldf(bias, hh * 16 + l, isb) * r;
        }
        WTb[((size_t)(m * 128 + j)) * 128 + i] = f2bf(acc * scale);
        if (i == 0) BC[m * 128 + j] = bacc * scale;
    }
}

// ---------------------------------------------------------------------------
// Fused MFMA QKV GEMM + CSR scan.
// Blocks 0..781: 64x128 GEMM, loop m=0..2 (A staged once); K accumulators
//   held through the V pass, KV stored interleaved ushort2.
// Blocks 782..879: CSR scan (512 nodes/block), last-block pattern -> BOFF.
// ---------------------------------------------------------------------------
#define NSB 98   // ceil(NN/512)
__global__ __launch_bounds__(256) void k_qkvscan(
    const void* __restrict__ h, const unsigned short* __restrict__ WTb,
    const float* __restrict__ BC, const int* __restrict__ FLAG,
    unsigned short* __restrict__ Qb, unsigned short* __restrict__ KVb,
    const unsigned* __restrict__ CNTP,
    unsigned* __restrict__ RPS, unsigned* __restrict__ BSUM,
    unsigned* __restrict__ BOFF, unsigned* __restrict__ DONE)
{
    __shared__ __align__(16) unsigned short Ah[64][136];   // +8 pad
    __shared__ __align__(16) unsigned short Bh[128][136];
    __shared__ int lastFlag;
    const int tid = threadIdx.x;

    if (blockIdx.x >= 782) {
        // ---------------- CSR scan part ----------------
        unsigned* shs = (unsigned*)&Ah[0][0];
        int sb = blockIdx.x - 782;
        int g0 = sb * 512 + tid * 2, g1 = g0 + 1;
        unsigned v0 = (g0 < NN) ? CNTP[(size_t)g0 << 4] : 0u;
        unsigned v1 = (g1 < NN) ? CNTP[(size_t)g1 << 4] : 0u;
        unsigned pv = v0 + v1;
        shs[tid] = pv;
        __syncthreads();
        #pragma unroll
        for (int off = 1; off < 256; off <<= 1) {
            unsigned t = 0;
            if (tid >= off) t = shs[tid - off];
            __syncthreads();
            if (tid >= off) shs[tid] += t;
            __syncthreads();
        }
        unsigned excl = shs[tid] - pv;
        if (g0 < NN) RPS[g0] = excl;
        if (g1 < NN) RPS[g1] = excl + v0;
        if (tid == 255) atomicExch(&BSUM[sb], shs[255]);
        __syncthreads();
        if (tid == 0) {
            __threadfence();
            lastFlag = (atomicAdd(DONE, 1u) == NSB - 1);
        }
        __syncthreads();
        if (!lastFlag) return;
        unsigned bv = (tid < NSB) ? atomicAdd(&BSUM[tid], 0u) : 0u;
        __syncthreads();
        shs[tid] = bv;
        __syncthreads();
        #pragma unroll
        for (int off = 1; off < 256; off <<= 1) {
            unsigned t = 0;
            if (tid >= off) t = shs[tid - off];
            __syncthreads();
            if (tid >= off) shs[tid] += t;
            __syncthreads();
        }
        if (tid < NSB) BOFF[tid] = shs[tid] - bv;
        return;
    }

    // ---------------- QKV GEMM part ----------------
    const int isb = FLAG[0];
    const int rowBase = blockIdx.x * 64;

    if (isb) {
        #pragma unroll
        for (int i = 0; i < 4; ++i) {
            int lin = tid + i * 256;
            int row = lin >> 4, kc = (lin & 15) * 8;
            int gr = rowBase + row;
            uint4 u = make_uint4(0, 0, 0, 0);
            if (gr < NN) u = *(const uint4*)((const unsigned short*)h + (size_t)gr * 128 + kc);
            *(uint4*)&Ah[row][kc] = u;
        }
    } else {
        #pragma unroll
        for (int i = 0; i < 8; ++i) {
            int lin = tid + i * 256;
            int row = lin >> 5, c4 = (lin & 31) * 4;
            int gr = rowBase + row;
            ushort4 o = make_ushort4(0, 0, 0, 0);
            if (gr < NN) {
                float4 f = *(const float4*)((const float*)h + (size_t)gr * 128 + c4);
                o.x = f2bf(f.x); o.y = f2bf(f.y); o.z = f2bf(f.z); o.w = f2bf(f.w);
            }
            *(ushort4*)&Ah[row][c4] = o;
        }
    }

    const int w = tid >> 6, l = tid & 63;
    const int lr = l & 15, q = l >> 4;
    v4f accK[8];

    for (int m = 0; m < 3; ++m) {
        if (m) __syncthreads();
        #pragma unroll
        for (int i = 0; i < 8; ++i) {
            int lin = tid + i * 256;
            int col = lin >> 4, kc = (lin & 15) * 8;
            uint4 u = *(const uint4*)(WTb + ((size_t)(m * 128 + col)) * 128 + kc);
            *(uint4*)&Bh[col][kc] = u;
        }
        __syncthreads();

        v4f acc[8];
        #pragma unroll
        for (int nt = 0; nt < 8; ++nt) {
            float bj = BC[m * 128 + nt * 16 + lr];
            acc[nt] = (v4f){bj, bj, bj, bj};
        }
        #pragma unroll
        for (int kk = 0; kk < 4; ++kk) {
            v8bf a = *(const v8bf*)&Ah[w * 16 + lr][kk * 32 + q * 8];
            #pragma unroll
            for (int nt = 0; nt < 8; ++nt) {
                v8bf b = *(const v8bf*)&Bh[nt * 16 + lr][kk * 32 + q * 8];
                acc[nt] = __builtin_amdgcn_mfma_f32_16x16x32_bf16(a, b, acc[nt], 0, 0, 0);
            }
        }
        if (m == 0) {
            #pragma unroll
            for (int nt = 0; nt < 8; ++nt)
                #pragma unroll
                for (int r = 0; r < 4; ++r) {
                    int row = rowBase + w * 16 + q * 4 + r;
                    if (row < NN)
                        Qb[(size_t)row * 128 + nt * 16 + lr] = f2bf(acc[nt][r]);
                }
        } else if (m == 1) {
            #pragma unroll
            for (int nt = 0; nt < 8; ++nt) accK[nt] = acc[nt];
        } else {
            #pragma unroll
            for (int nt = 0; nt < 8; ++nt)
                #pragma unroll
                for (int r = 0; r < 4; ++r) {
                    int row = rowBase + w * 16 + q * 4 + r;
                    if (row < NN) {
                        ushort2 kv;
                        kv.x = f2bf(accK[nt][r]);   // K channel
                        kv.y = f2bf(acc[nt][r]);    // V channel
                        *(ushort2*)&KVb[(size_t)row * 256 + (nt * 16 + lr) * 2] = kv;
                    }
                }
        }
    }
}

// ---------------------------------------------------------------------------
// CSR fill, ATOMIC-FREE: pos = RPS[d] + BOFF + RANKS[e]. ESRC is ushort
// (src < 50000 < 65536): 1.6 MB footprint stays L2-resident per XCD.
// 2 edges/thread, coalesced index/rank loads.
// ---------------------------------------------------------------------------
__global__ __launch_bounds__(256) void k_fill(
    const int* __restrict__ src, const int* __restrict__ dst,
    const unsigned short* __restrict__ RANKS,
    const unsigned* __restrict__ RPS, const unsigned* __restrict__ BOFF,
    unsigned short* __restrict__ ESRC)
{
    int t = blockIdx.x * 256 + threadIdx.x;
    if (t >= NE / 2) return;
    int e = t * 2;
    const int2 d2 = *(const int2*)(dst + e);
    const int2 s2 = *(const int2*)(src + e);
    const ushort2 r2 = *(const ushort2*)(RANKS + e);
    unsigned p0 = RPS[d2.x] + BOFF[d2.x >> 9] + r2.x;
    unsigned p1 = RPS[d2.y] + BOFF[d2.y >> 9] + r2.y;
    ESRC[p0] = (unsigned short)s2.x;
    ESRC[p1] = (unsigned short)s2.y;
}

// ---------------------------------------------------------------------------
// Fused attention: one wave per dst node, 32 lanes per edge (2 edges/round),
// batch-4 rounds (8 edges), software-pipelined gathers. No-max softmax.
// ---------------------------------------------------------------------------
__global__ __launch_bounds__(256) void k_attn(
    const unsigned* __restrict__ RPS, const unsigned* __restrict__ BOFF,
    const unsigned short* __restrict__ ESRC,
    const unsigned short* __restrict__ Qb, const unsigned short* __restrict__ KVb,
    unsigned short* __restrict__ Tb)
{
    int d = (blockIdx.x * 256 + threadIdx.x) >> 6;
    int lane = threadIdx.x & 63;
    int hl = lane >> 5;        // which edge of the pair
    int sub = lane & 31;       // channel group: channels sub*4 .. sub*4+3
    int beg = (int)(RPS[d] + BOFF[d >> 9]);
    int end = (d == NN - 1) ? NE : (int)(RPS[d + 1] + BOFF[(d + 1) >> 9]);
    const float LOG2E = 1.4426950408889634f;

    const ushort4 qu = *(const ushort4*)(Qb + (size_t)d * 128 + sub * 4);
    float q0 = bf2f(qu.x) * LOG2E, q1 = bf2f(qu.y) * LOG2E;
    float q2 = bf2f(qu.z) * LOG2E, q3 = bf2f(qu.w) * LOG2E;

    float s = 0.f, o0 = 0.f, o1 = 0.f, o2 = 0.f, o3 = 0.f;
    v8us kvA[4]; int vA[4];
    if (beg < end) {
        #pragma unroll
        for (int t = 0; t < 4; ++t) {
            int idx = beg + 2 * t + hl;
            vA[t] = idx < end;
            int sid = ESRC[vA[t] ? idx : end - 1];
            kvA[t] = *(const v8us*)(KVb + (size_t)sid * 256 + sub * 8);
        }
    }
    for (int j = beg; j < end; j += 8) {
        v8us kvB[4]; int vB[4] = {0, 0, 0, 0};
        int jn = j + 8;
        if (jn < end) {                   // issue next round's gathers NOW
            #pragma unroll
            for (int t = 0; t < 4; ++t) {
                int idx = jn + 2 * t + hl;
                vB[t] = idx < end;
                int sid = ESRC[vB[t] ? idx : end - 1];
                kvB[t] = *(const v8us*)(KVb + (size_t)sid * 256 + sub * 8);
            }
        }
        #pragma unroll
        for (int t = 0; t < 4; ++t) {
            float p = q0 * bf2f(kvA[t][0]) + q1 * bf2f(kvA[t][2])
                    + q2 * bf2f(kvA[t][4]) + q3 * bf2f(kvA[t][6]);
            p += __shfl_xor(p, 1);
            p += __shfl_xor(p, 2);       // per-head score in 4-lane group
            float w = vA[t] ? EXP2F(p) : 0.f;
            s  += w;
            o0 += w * bf2f(kvA[t][1]);
            o1 += w * bf2f(kvA[t][3]);
            o2 += w * bf2f(kvA[t][5]);
            o3 += w * bf2f(kvA[t][7]);
        }
        #pragma unroll
        for (int t = 0; t < 4; ++t) { kvA[t] = kvB[t]; vA[t] = vB[t]; }
    }
    // combine the two 32-lane halves
    s  += __shfl_xor(s, 32);
    o0 += __shfl_xor(o0, 32);
    o1 += __shfl_xor(o1, 32);
    o2 += __shfl_xor(o2, 32);
    o3 += __shfl_xor(o3, 32);
    float r = (s > 0.f) ? (1.0f / s) : 0.f;
    if (hl == 0) {
        ushort4 o;
        o.x = f2bf(o0 * r); o.y = f2bf(o1 * r);
        o.z = f2bf(o2 * r); o.w = f2bf(o3 * r);
        *(ushort4*)(Tb + (size_t)d * 128 + sub * 4) = o;
    }
}

// ---------------------------------------------------------------------------
// MFMA final GEMM + sigmoid-skip blend. T is bf16 (A-tile copied raw).
// ---------------------------------------------------------------------------
__global__ __launch_bounds__(256) void k_final_m(
    const unsigned short* __restrict__ Tb, const unsigned short* __restrict__ WTb,
    const float* __restrict__ BC, const void* __restrict__ h,
    const void* __restrict__ skip, const int* __restrict__ FLAG,
    void* __restrict__ out)
{
    __shared__ __align__(16) unsigned short Ah[64][136];
    __shared__ __align__(16) unsigned short Bh[128][136];
    const int isb = FLAG[0];
    const int tid = threadIdx.x;
    const int rowBase = blockIdx.x * 64;

    #pragma unroll
    for (int i = 0; i < 4; ++i) {
        int lin = tid + i * 256;
        int row = lin >> 4, kc = (lin & 15) * 8;
        int gr = rowBase + row;
        uint4 u = make_uint4(0, 0, 0, 0);
        if (gr < NN) u = *(const uint4*)(Tb + (size_t)gr * 128 + kc);
        *(uint4*)&Ah[row][kc] = u;
    }
    #pragma unroll
    for (int i = 0; i < 8; ++i) {
        int lin = tid + i * 256;
        int col = lin >> 4, kc = (lin & 15) * 8;
        uint4 u = *(const uint4*)(WTb + ((size_t)(3 * 128 + col)) * 128 + kc);
        *(uint4*)&Bh[col][kc] = u;
    }
    __syncthreads();

    const int w = tid >> 6, l = tid & 63;
    const int lr = l & 15, q = l >> 4;
    v4f acc[8];
    #pragma unroll
    for (int nt = 0; nt < 8; ++nt) {
        float bj = BC[3 * 128 + nt * 16 + lr];
        acc[nt] = (v4f){bj, bj, bj, bj};
    }
    #pragma unroll
    for (int kk = 0; kk < 4; ++kk) {
        v8bf a = *(const v8bf*)&Ah[w * 16 + lr][kk * 32 + q * 8];
        #pragma unroll
        for (int nt = 0; nt < 8; ++nt) {
            v8bf b = *(const v8bf*)&Bh[nt * 16 + lr][kk * 32 + q * 8];
            acc[nt] = __builtin_amdgcn_mfma_f32_16x16x32_bf16(a, b, acc[nt], 0, 0, 0);
        }
    }
    float skipv = ldf(skip, 0, isb);
    float alpha = 1.0f / (1.0f + __expf(-skipv));
    float beta = 1.0f - alpha;
    #pragma unroll
    for (int nt = 0; nt < 8; ++nt) {
        #pragma unroll
        for (int r = 0; r < 4; ++r) {
            int row = rowBase + w * 16 + q * 4 + r;
            if (row < NN) {
                size_t off = (size_t)row * 128 + nt * 16 + lr;
                float hv = ldf(h, off, isb);
                float o = alpha * acc[nt][r] + beta * hv;
                if (isb) ((unsigned short*)out)[off] = f2bf(o);
                else     ((float*)out)[off] = o;
            }
        }
    }
}

// ---------------------------------------------------------------------------
// ws layout (u32 offsets): FLAG 16 | BC 512 | WTb 32768 | CNTP 800000 |
// DONE 16 | RANKS 400000 (800000 ushort) | RPS 50048 | BSUM 128 | BOFF 128 |
// Tb NN*128us | ESRC NE ushort | Qb NN*128us | KVb NN*256us   total ~58 MB
// ---------------------------------------------------------------------------
extern "C" void kernel_launch(void* const* d_in, const int* in_sizes, int n_in,
                              void* d_out, int out_size, void* d_ws, size_t ws_size,
                              hipStream_t stream)
{
    const void* h  = d_in[0];
    const int* src = (const int*)d_in[1];
    const int* dst = (const int*)d_in[2];
    const void* Wk = d_in[3];
    const void* bk = d_in[4];
    const void* Wq = d_in[5];
    const void* bq = d_in[6];
    const void* Wv = d_in[7];
    const void* bv = d_in[8];
    const void* Wa = d_in[9];
    const void* ba = d_in[10];
    const void* rel_att = d_in[11];
    const void* rel_msg = d_in[12];
    const void* rel_pri = d_in[13];
    const void* skip    = d_in[14];

    float* F = (float*)d_ws;
    int* FLAG      = (int*)F;
    float* BC      = F + 16;
    unsigned short* WTb = (unsigned short*)(BC + 512);
    unsigned* CNTP = (unsigned*)((float*)(BC + 512) + 32768);
    unsigned* DONE = CNTP + 800000;
    unsigned short* RANKS = (unsigned short*)(DONE + 16);
    unsigned* RPS  = (unsigned*)(RANKS + 800000);
    unsigned* BSUM = RPS + 50048;
    unsigned* BOFF = BSUM + 128;
    unsigned short* Tb = (unsigned short*)(BOFF + 128);
    unsigned short* ESRC = Tb + (size_t)NN * 128;
    unsigned short* Qb  = ESRC + NE;
    unsigned short* KVb = Qb + (size_t)NN * 128;

    // zero CNTP | DONE (contiguous, 3.2 MB)
    (void)hipMemsetAsync(CNTP, 0, (800000 + 16) * sizeof(unsigned), stream);

    k_prep<<<512 + 6250, 128, 0, stream>>>(Wq, bq, Wk, bk, Wv, bv, Wa, ba,
                                           rel_att, rel_msg, rel_pri, dst,
                                           CNTP, RANKS, FLAG, WTb, BC);
    k_qkvscan<<<782 + NSB, 256, 0, stream>>>(h, WTb, BC, FLAG, Qb, KVb,
                                             CNTP, RPS, BSUM, BOFF, DONE);
    k_fill<<<(NE / 2 + 255) / 256, 256, 0, stream>>>(src, dst, RANKS, RPS, BOFF, ESRC);
    k_attn<<<(NN * 64) / 256, 256, 0, stream>>>(RPS, BOFF, ESRC, Qb, KVb, Tb);
    k_final_m<<<782, 256, 0, stream>>>(Tb, WTb, BC, h, skip, FLAG, d_out);
}